// Round 6
// baseline (774.551 us; speedup 1.0000x reference)
//
#include <hip/hip_runtime.h>
#include <math.h>

// Problem constants (fixed by the reference)
#define BN 256     // batch N
#define TT 1000    // timesteps
#define NO 10      // obs dim
#define NS 10      // state dim
#define HID 64     // GRU hidden
#define DIN 20     // NO + NS
#define G3 192     // 3*HID
#define GS 8       // steps per staged input group (fallback kernel)
#define NG 125     // groups (fallback kernel)
#define SPW 16     // samples per block (MFMA M dimension)
#define NBLK (BN / SPW)   // 16 blocks

using bf16x8 = __attribute__((ext_vector_type(8))) short;
using f32x4  = __attribute__((ext_vector_type(4))) float;

__device__ __forceinline__ float rcpf(float x) { return __builtin_amdgcn_rcpf(x); }
// workgroup barrier without the vmcnt(0) drain __syncthreads() emits;
// global loads/stores issued before it stay in flight (prefetch survives).
__device__ __forceinline__ void sync_lds() {
    asm volatile("s_waitcnt lgkmcnt(0)\n\ts_barrier" ::: "memory");
}
__device__ __forceinline__ unsigned cvt_pk_bf16(float a, float b) {   // lo<-a, hi<-b
    unsigned r;
    asm("v_cvt_pk_bf16_f32 %0, %1, %2" : "=v"(r) : "v"(a), "v"(b));
    return r;
}
__device__ __forceinline__ short f2bf(float f) {   // RNE f32->bf16 (init path only)
    unsigned u = __float_as_uint(f);
    return (short)((u + 0x7fffu + ((u >> 16) & 1u)) >> 16);
}
#define MFMA16 __builtin_amdgcn_mfma_f32_16x16x32_bf16

// ---------------- xproj precompute: x @ Wi + bias, all (n,t) ---------------
// R6 theory: the x-projection is h-independent; inside the serial loop it
// costs 3 MFMAs issue + 1 extra chained MFMA latency + all input staging.
// Hoist it: 2000 blocks x 1 wave, each does (16 samples, 8 steps) x 192
// units = 96 MFMAs. Output layout [g][t][u(192)][s(16)] f32 with bias
// folded (bi+bh for r/z units u<128, bi only for n units) so the
// recurrence's accumulator init is one coalesced dwordx4 load: the D-row
// (= sample = lg*4+reg) maps exactly onto 4 consecutive s dwords.
__global__ __launch_bounds__(64)
void xproj_pre(const float* __restrict__ Yi, const float* __restrict__ Xh,
               const float* __restrict__ Wi, const float* __restrict__ bi,
               const float* __restrict__ bh, float* __restrict__ xp) {
    const int tid = threadIdx.x;
    const int l15 = tid & 15, lg = tid >> 4;
    const int g  = blockIdx.x / 125;       // sample group 0..15
    const int tc = blockIdx.x % 125;       // 8-step chunk

    // staged inputs: [t][s][32 dim-slots] bf16; slots 0..9 = y, 10..19 = x,
    // 20..31 = ZERO pad (k-map is identity; B has zeros there too)
    __shared__ __align__(16) ushort xs[8][16][32];   // 8 KB

    // B fragments: 12 unit-tiles; k = lg*8+e = input dim (k<20) else 0
    bf16x8 B[12];
    float bc[12];
#pragma unroll
    for (int tile = 0; tile < 12; ++tile) {
        const int u = tile * 16 + l15;
#pragma unroll
        for (int e = 0; e < 8; ++e) {
            const int k = lg * 8 + e;
            B[tile][e] = (k < 20) ? f2bf(Wi[k * G3 + u]) : (short)0;
        }
        bc[tile] = bi[u] + ((u < 128) ? bh[u] : 0.0f);
    }

    // stage: thread (s = tid&15, tt = tid>>4) handles t = tt and tt+4
    {
        const int s = tid & 15, tt = tid >> 4;
#pragma unroll
        for (int rep = 0; rep < 2; ++rep) {
            const int t = tt + 4 * rep;
            const float* yp = Yi + ((size_t)(g * 16 + s) * TT + (tc * 8 + t)) * NO;
            const float* xq = Xh + ((size_t)(g * 16 + s) * TT + (tc * 8 + t)) * NS;
            float y[10], x[10];
#pragma unroll
            for (int i = 0; i < 10; ++i) { y[i] = yp[i]; x[i] = xq[i]; }
            uint4 a, b, c;
            a.x = cvt_pk_bf16(y[0], y[1]); a.y = cvt_pk_bf16(y[2], y[3]);
            a.z = cvt_pk_bf16(y[4], y[5]); a.w = cvt_pk_bf16(y[6], y[7]);
            b.x = cvt_pk_bf16(y[8], y[9]); b.y = cvt_pk_bf16(x[0], x[1]);
            b.z = cvt_pk_bf16(x[2], x[3]); b.w = cvt_pk_bf16(x[4], x[5]);
            c.x = cvt_pk_bf16(x[6], x[7]); c.y = cvt_pk_bf16(x[8], x[9]);
            c.z = 0u; c.w = 0u;
            uint4* wp = (uint4*)&xs[t][s][0];
            wp[0] = a; wp[1] = b; wp[2] = c; wp[3] = make_uint4(0u, 0u, 0u, 0u);
        }
    }
    sync_lds();

    float* outg = xp + (size_t)g * TT * 3072 + (size_t)(tc * 8) * 3072;
#pragma unroll
    for (int t = 0; t < 8; ++t) {
        const bf16x8 A = *(const bf16x8*)&xs[t][l15][lg * 8];   // row = sample
        float* outt = outg + (size_t)t * 3072 + lg * 4;
#pragma unroll
        for (int tile = 0; tile < 12; ++tile) {
            f32x4 acc = {bc[tile], bc[tile], bc[tile], bc[tile]};
            acc = MFMA16(A, B[tile], acc, 0, 0, 0);
            // D rows lg*4+r = samples -> 4 consecutive s dwords: one dwordx4,
            // instruction covers a contiguous 1KB tile (perfect coalescing)
            *(f32x4*)(outt + (size_t)(tile * 16 + l15) * 16) = acc;
        }
    }
}

// ---------------- Phase 1 (XP path): recurrence only -----------------------
// Step: 2 h-fragment b128 reads, 6 MFMAs in 3 PARALLEL pairs (+2 amv for
// waves 0/1), f32x4 adds, nonlinearity, 4 b16 h-writes, one lgkm barrier.
// Chain depth: 1 MFMA (was 3 in R5). xproj arrives via 2-step-deep
// prefetched dwordx4 loads (~900cy in flight, covers HBM; they survive the
// lgkm-only barrier). h exchange machinery is VERBATIM the verified R5 code.
__global__ __launch_bounds__(256)
void gru_rec(const float* __restrict__ Wh, const float* __restrict__ bh,
             const float* __restrict__ Wmu, const float* __restrict__ Wvar,
             const float* __restrict__ xp, float* __restrict__ mv_out) {
    const int tid = threadIdx.x;
    const int lane = tid & 63;
    const int w   = tid >> 6;      // wave 0..3, owns units 16w..16w+16
    const int l15 = lane & 15;
    const int lg  = lane >> 4;
    const int g   = blockIdx.x;
    const int n0  = g * SPW;

    __shared__ __align__(16) ushort hb[2][16 * 64];          // 4 KB

    const int u = 16 * w + l15;
    bf16x8 Bhr0, Bhr1, Bhz0, Bhz1, Bhn0, Bhn1;
#pragma unroll
    for (int e = 0; e < 8; ++e) {
        const int k0 = lg * 8 + e, k1 = 32 + lg * 8 + e;
        Bhr0[e] = f2bf(Wh[k0 * G3 + u]);       Bhr1[e] = f2bf(Wh[k1 * G3 + u]);
        Bhz0[e] = f2bf(Wh[k0 * G3 + 64 + u]);  Bhz1[e] = f2bf(Wh[k1 * G3 + 64 + u]);
        Bhn0[e] = f2bf(Wh[k0 * G3 + 128 + u]); Bhn1[e] = f2bf(Wh[k1 * G3 + 128 + u]);
    }
    bf16x8 Bmv0 = {}, Bmv1 = {};   // waves 0,1: mv cols 0..15 / 16..19(+pad)
    if (w < 2) {
        const int c = 16 * w + l15;
#pragma unroll
        for (int e = 0; e < 8; ++e) {
            const int k0 = lg * 8 + e, k1 = 32 + lg * 8 + e;
            float v0 = 0.f, v1 = 0.f;
            if (c < 10)      { v0 = Wmu[k0 * NS + c];        v1 = Wmu[k1 * NS + c]; }
            else if (c < 20) { v0 = Wvar[k0 * NS + (c - 10)]; v1 = Wvar[k1 * NS + (c - 10)]; }
            Bmv0[e] = f2bf(v0); Bmv1[e] = f2bf(v1);
        }
    }
    const float bnh = bh[128 + u];

    // h-exchange LDS addressing (verbatim R5, verified)
    const int hro0 = l15 * 64 + (((0 + lg) ^ (l15 & 7)) << 3);
    const int hro1 = l15 * 64 + (((4 + lg) ^ (l15 & 7)) << 3);
    int hwo[4];
#pragma unroll
    for (int r = 0; r < 4; ++r) {
        const int s = 4 * lg + r;
        hwo[r] = s * 64 + ((((u >> 3)) ^ (s & 7)) << 3) + (u & 7);
    }

    // zero h buffers
    {
        ushort* hf = (ushort*)hb;
        for (int i = tid; i < 2 * 16 * 64; i += 256) hf[i] = 0;
    }
    sync_lds();

    const float* xpg = xp + (size_t)g * TT * 3072;
    const int xo = u * 16 + 4 * lg;            // r-gate dword offset in a t-slab
    // 2-deep prefetch: set A = even t, set B = odd t
    f32x4 xrA = *(const f32x4*)(xpg + xo);
    f32x4 xzA = *(const f32x4*)(xpg + 1024 + xo);
    f32x4 xnA = *(const f32x4*)(xpg + 2048 + xo);
    f32x4 xrB = *(const f32x4*)(xpg + 3072 + xo);
    f32x4 xzB = *(const f32x4*)(xpg + 3072 + 1024 + xo);
    f32x4 xnB = *(const f32x4*)(xpg + 3072 + 2048 + xo);

    float hreg[4] = {0.f, 0.f, 0.f, 0.f};
    const f32x4 z4 = {0.f, 0.f, 0.f, 0.f};

#define STEP(T, XR, XZ, XN)                                                    \
    {                                                                          \
        const int t = (T);                                                     \
        const int p = t & 1;                                                   \
        const bf16x8 h0 = *(const bf16x8*)((const ushort*)hb[p] + hro0);       \
        const bf16x8 h1 = *(const bf16x8*)((const ushort*)hb[p] + hro1);       \
        f32x4 aR = MFMA16(h0, Bhr0, XR, 0, 0, 0);                              \
        f32x4 bR = MFMA16(h1, Bhr1, z4, 0, 0, 0);                              \
        f32x4 aZ = MFMA16(h0, Bhz0, XZ, 0, 0, 0);                              \
        f32x4 bZ = MFMA16(h1, Bhz1, z4, 0, 0, 0);                              \
        f32x4 aH = MFMA16(h0, Bhn0, (f32x4){bnh, bnh, bnh, bnh}, 0, 0, 0);     \
        f32x4 bH = MFMA16(h1, Bhn1, z4, 0, 0, 0);                              \
        const f32x4 axv = XN;                                                  \
        {                                                                      \
            const int tl = (t + 2 < TT) ? (t + 2) : (TT - 1);                  \
            const float* pb = xpg + (size_t)tl * 3072;                         \
            XR = *(const f32x4*)(pb + xo);                                     \
            XZ = *(const f32x4*)(pb + 1024 + xo);                              \
            XN = *(const f32x4*)(pb + 2048 + xo);                              \
        }                                                                      \
        if (w < 2) {                                                           \
            f32x4 amv = MFMA16(h0, Bmv0, z4, 0, 0, 0);                         \
            amv = MFMA16(h1, Bmv1, amv, 0, 0, 0);                              \
            if (t > 0) {                                                       \
                _Pragma("unroll")                                              \
                for (int r = 0; r < 4; ++r) {                                  \
                    const size_t smp = (size_t)(n0 + 4 * lg + r);              \
                    if (w == 0)                                                \
                        mv_out[(smp * TT + (t - 1)) * DIN + l15] = amv[r];     \
                    else if (l15 < 4)                                          \
                        mv_out[(smp * TT + (t - 1)) * DIN + 16 + l15] = amv[r];\
                }                                                              \
            }                                                                  \
        }                                                                      \
        _Pragma("unroll")                                                      \
        for (int r = 0; r < 4; ++r) {                                          \
            const float ar = aR[r] + bR[r];                                    \
            const float az = aZ[r] + bZ[r];                                    \
            const float ah = aH[r] + bH[r];                                    \
            const float rr  = rcpf(1.f + __expf(-ar));                         \
            const float zz  = rcpf(1.f + __expf(-az));                         \
            const float pre = fmaf(rr, ah, axv[r]);                            \
            const float e2  = __expf(2.f * pre);                               \
            const float nn  = 1.f - 2.f * rcpf(e2 + 1.f);                      \
            hreg[r] = fmaf(zz, hreg[r] - nn, nn);                              \
        }                                                                      \
        const unsigned pk01 = cvt_pk_bf16(hreg[0], hreg[1]);                   \
        const unsigned pk23 = cvt_pk_bf16(hreg[2], hreg[3]);                   \
        ushort* hw = (ushort*)hb[p ^ 1];                                       \
        hw[hwo[0]] = (ushort)pk01;                                             \
        hw[hwo[1]] = (ushort)(pk01 >> 16);                                     \
        hw[hwo[2]] = (ushort)pk23;                                             \
        hw[hwo[3]] = (ushort)(pk23 >> 16);                                     \
        sync_lds();                                                            \
    }

#pragma unroll 1
    for (int tt = 0; tt < TT / 2; ++tt) {
        STEP(2 * tt,     xrA, xzA, xnA)
        STEP(2 * tt + 1, xrB, xzB, xnB)
    }
#undef STEP

    // epilogue: mv for t=999 from h_999 (in hb[0] after the last step)
    if (w < 2) {
        const bf16x8 h0 = *(const bf16x8*)((const ushort*)hb[0] + hro0);
        const bf16x8 h1 = *(const bf16x8*)((const ushort*)hb[0] + hro1);
        f32x4 amv = MFMA16(h0, Bmv0, z4, 0, 0, 0);
        amv = MFMA16(h1, Bmv1, amv, 0, 0, 0);
#pragma unroll
        for (int r = 0; r < 4; ++r) {
            const size_t smp = (size_t)(n0 + 4 * lg + r);
            if (w == 0)
                mv_out[(smp * TT + (TT - 1)) * DIN + l15] = amv[r];
            else if (l15 < 4)
                mv_out[(smp * TT + (TT - 1)) * DIN + 16 + l15] = amv[r];
        }
    }
}

// Stage one (sample, step, half) row: 16 bf16 slots, PADS WRITTEN AS ZERO.
__device__ __forceinline__ void stage16(ushort* wp, float2 L0, float2 L1,
                                        float2 L2, float2 L3, float2 L4) {
    uint4 a, b;
    a.x = cvt_pk_bf16(L0.x, L0.y);
    a.y = cvt_pk_bf16(L1.x, L1.y);
    a.z = cvt_pk_bf16(L2.x, 0.f);
    a.w = 0u;
    b.x = cvt_pk_bf16(L2.y, L3.x);
    b.y = cvt_pk_bf16(L3.y, L4.x);
    b.z = cvt_pk_bf16(L4.y, 0.f);
    b.w = 0u;
    *(uint4*)(wp)     = a;
    *(uint4*)(wp + 8) = b;
}

// ---------------- Phase 1 fallback (verbatim R5, verified): used if the ----
// ---------------- workspace is too small for the xproj buffer --------------
__global__ __launch_bounds__(256)
void gru_mfma_fb(const float* __restrict__ Yi, const float* __restrict__ Xh,
                 const float* __restrict__ Wi, const float* __restrict__ Wh,
                 const float* __restrict__ bi, const float* __restrict__ bh,
                 const float* __restrict__ Wmu, const float* __restrict__ Wvar,
                 float* __restrict__ mv_out) {
    const int tid = threadIdx.x;
    const int lane = tid & 63;
    const int w   = tid >> 6;
    const int l15 = lane & 15;
    const int lg  = lane >> 4;
    const int n0  = blockIdx.x * SPW;

    __shared__ __align__(16) ushort hb[2][16 * 64];
    __shared__ __align__(16) ushort xb[2][GS][16][32];

    const int u = 16 * w + l15;
    bf16x8 Bxr, Bxz, Bxn, Bhr0, Bhr1, Bhz0, Bhz1, Bhn0, Bhn1;
#pragma unroll
    for (int e = 0; e < 8; ++e) {
        const int d = lg * 5 + e;
        Bxr[e] = (e < 5) ? f2bf(Wi[d * G3 + u])       : (short)0;
        Bxz[e] = (e < 5) ? f2bf(Wi[d * G3 + 64 + u])  : (short)0;
        Bxn[e] = (e < 5) ? f2bf(Wi[d * G3 + 128 + u]) : (short)0;
        const int k0 = lg * 8 + e, k1 = 32 + lg * 8 + e;
        Bhr0[e] = f2bf(Wh[k0 * G3 + u]);       Bhr1[e] = f2bf(Wh[k1 * G3 + u]);
        Bhz0[e] = f2bf(Wh[k0 * G3 + 64 + u]);  Bhz1[e] = f2bf(Wh[k1 * G3 + 64 + u]);
        Bhn0[e] = f2bf(Wh[k0 * G3 + 128 + u]); Bhn1[e] = f2bf(Wh[k1 * G3 + 128 + u]);
    }
    bf16x8 Bmv0 = {}, Bmv1 = {};
    if (w < 2) {
        const int c = 16 * w + l15;
#pragma unroll
        for (int e = 0; e < 8; ++e) {
            const int k0 = lg * 8 + e, k1 = 32 + lg * 8 + e;
            float v0 = 0.f, v1 = 0.f;
            if (c < 10)      { v0 = Wmu[k0 * NS + c];        v1 = Wmu[k1 * NS + c]; }
            else if (c < 20) { v0 = Wvar[k0 * NS + (c - 10)]; v1 = Wvar[k1 * NS + (c - 10)]; }
            Bmv0[e] = f2bf(v0); Bmv1[e] = f2bf(v1);
        }
    }
    const float br  = bi[u] + bh[u];
    const float bz  = bi[64 + u] + bh[64 + u];
    const float bnx = bi[128 + u];
    const float bnh = bh[128 + u];

    const int hro0 = l15 * 64 + (((0 + lg) ^ (l15 & 7)) << 3);
    const int hro1 = l15 * 64 + (((4 + lg) ^ (l15 & 7)) << 3);
    int hwo[4];
#pragma unroll
    for (int r = 0; r < 4; ++r) {
        const int s = 4 * lg + r;
        hwo[r] = s * 64 + ((((u >> 3)) ^ (s & 7)) << 3) + (u & 7);
    }

    const int ss   = tid >> 4;
    const int ii   = tid & 15;
    const int st_t = ii >> 1;
    const int sh   = ii & 1;
    const float* src_base = sh ? (Xh + (size_t)(n0 + ss) * TT * NS)
                               : (Yi + (size_t)(n0 + ss) * TT * NO);

    {
        ushort* hf = (ushort*)hb;
        for (int i = tid; i < 2 * 16 * 64; i += 256) hf[i] = 0;
        const float* p = src_base + (size_t)st_t * 10;
        const float2 L0 = *(const float2*)(p);
        const float2 L1 = *(const float2*)(p + 2);
        const float2 L2 = *(const float2*)(p + 4);
        const float2 L3 = *(const float2*)(p + 6);
        const float2 L4 = *(const float2*)(p + 8);
        stage16(&xb[0][st_t][ss][sh * 16], L0, L1, L2, L3, L4);
        sync_lds();
    }

    float hreg[4] = {0.f, 0.f, 0.f, 0.f};

#pragma unroll 1
    for (int g = 0; g < NG; ++g) {
        const int bq = g & 1;
        float2 L0, L1, L2, L3, L4;
        const bool do_ld = (g + 1 < NG);
        if (do_ld) {
            const float* p = src_base + (size_t)((g + 1) * GS + st_t) * 10;
            L0 = *(const float2*)(p);     L1 = *(const float2*)(p + 2);
            L2 = *(const float2*)(p + 4); L3 = *(const float2*)(p + 6);
            L4 = *(const float2*)(p + 8);
        }

#pragma unroll
        for (int st = 0; st < GS; ++st) {
            const int p = st & 1;
            const int t = 8 * g + st;
            const bf16x8 xa = *(const bf16x8*)&xb[bq][st][l15][lg * 8];
            const bf16x8 h0 = *(const bf16x8*)((const ushort*)hb[p] + hro0);
            const bf16x8 h1 = *(const bf16x8*)((const ushort*)hb[p] + hro1);

            f32x4 ar = {br, br, br, br}, az = {bz, bz, bz, bz};
            f32x4 ax = {bnx, bnx, bnx, bnx}, ah = {bnh, bnh, bnh, bnh};
            ar = MFMA16(xa, Bxr, ar, 0, 0, 0);
            az = MFMA16(xa, Bxz, az, 0, 0, 0);
            ax = MFMA16(xa, Bxn, ax, 0, 0, 0);
            ar = MFMA16(h0, Bhr0, ar, 0, 0, 0);
            az = MFMA16(h0, Bhz0, az, 0, 0, 0);
            ah = MFMA16(h0, Bhn0, ah, 0, 0, 0);
            ar = MFMA16(h1, Bhr1, ar, 0, 0, 0);
            az = MFMA16(h1, Bhz1, az, 0, 0, 0);
            ah = MFMA16(h1, Bhn1, ah, 0, 0, 0);
            if (w < 2) {
                f32x4 amv = {0.f, 0.f, 0.f, 0.f};
                amv = MFMA16(h0, Bmv0, amv, 0, 0, 0);
                amv = MFMA16(h1, Bmv1, amv, 0, 0, 0);
                if (t > 0) {
#pragma unroll
                    for (int r = 0; r < 4; ++r) {
                        const size_t smp = (size_t)(n0 + 4 * lg + r);
                        if (w == 0)
                            mv_out[(smp * TT + (t - 1)) * DIN + l15] = amv[r];
                        else if (l15 < 4)
                            mv_out[(smp * TT + (t - 1)) * DIN + 16 + l15] = amv[r];
                    }
                }
            }
#pragma unroll
            for (int r = 0; r < 4; ++r) {
                const float rr  = rcpf(1.f + __expf(-ar[r]));
                const float zz  = rcpf(1.f + __expf(-az[r]));
                const float pre = fmaf(rr, ah[r], ax[r]);
                const float e2  = __expf(2.f * pre);
                const float nn  = 1.f - 2.f * rcpf(e2 + 1.f);
                hreg[r] = fmaf(zz, hreg[r] - nn, nn);
            }
            const unsigned pk01 = cvt_pk_bf16(hreg[0], hreg[1]);
            const unsigned pk23 = cvt_pk_bf16(hreg[2], hreg[3]);
            ushort* hw = (ushort*)hb[p ^ 1];
            hw[hwo[0]] = (ushort)pk01;
            hw[hwo[1]] = (ushort)(pk01 >> 16);
            hw[hwo[2]] = (ushort)pk23;
            hw[hwo[3]] = (ushort)(pk23 >> 16);
            if (st == GS - 1 && do_ld)
                stage16(&xb[bq ^ 1][st_t][ss][sh * 16], L0, L1, L2, L3, L4);
            sync_lds();
        }
    }

    if (w < 2) {
        const bf16x8 h0 = *(const bf16x8*)((const ushort*)hb[0] + hro0);
        const bf16x8 h1 = *(const bf16x8*)((const ushort*)hb[0] + hro1);
        f32x4 amv = {0.f, 0.f, 0.f, 0.f};
        amv = MFMA16(h0, Bmv0, amv, 0, 0, 0);
        amv = MFMA16(h1, Bmv1, amv, 0, 0, 0);
#pragma unroll
        for (int r = 0; r < 4; ++r) {
            const size_t smp = (size_t)(n0 + 4 * lg + r);
            if (w == 0)
                mv_out[(smp * TT + (TT - 1)) * DIN + l15] = amv[r];
            else if (l15 < 4)
                mv_out[(smp * TT + (TT - 1)) * DIN + 16 + l15] = amv[r];
        }
    }
}

// ---------------- d_out init: the constant term ----------------------------
__global__ void init_out(float* out) {
    out[0] = -0.918938533204672742f;   // -0.5*log(2pi)
}

// ---------------- Phase 2: per-(n,t) Gaussian log-lik (unchanged) ----------
__global__ __launch_bounds__(256)
void lik_phase2(const float* __restrict__ Yi, const float* __restrict__ Cw,
                const float* __restrict__ Hm, const float* __restrict__ mu_w,
                const float* __restrict__ b_mu, const float* __restrict__ b_var,
                const float* __restrict__ mv_in, float* __restrict__ out) {
    __shared__ float sH[NO * NS];
    __shared__ float smw[NO], sbm[NS], sbv[NS];
    __shared__ float ssum[4];
    const int tid = threadIdx.x;
    if (tid < NO * NS) sH[tid] = Hm[tid];
    if (tid < NO) smw[tid] = mu_w[tid];
    if (tid < NS) { sbm[tid] = b_mu[tid]; sbv[tid] = b_var[tid]; }
    __syncthreads();

    const int gid = blockIdx.x * 256 + tid;
    float contrib = 0.0f;
    if (gid < BN * TT) {
        const int n = gid / TT;
        const float* mv = mv_in + (size_t)gid * DIN;
        float mu[NS], va[NS];
#pragma unroll
        for (int i = 0; i < NS; ++i) {
            mu[i] = mv[i] + sbm[i];
            float x = mv[NS + i] + sbv[i];
            va[i] = (x > 0.0f) ? (x + log1pf(__expf(-x))) : log1pf(__expf(x));
        }
        const float* y = Yi + (size_t)gid * NO;
        float e[NO];
#pragma unroll
        for (int i = 0; i < NO; ++i) {
            float m = smw[i];
#pragma unroll
            for (int j = 0; j < NS; ++j) m = fmaf(sH[i * NS + j], mu[j], m);
            e[i] = y[i] - m;
        }
        float M[NO][NO];
        const float* cw = Cw + (size_t)n * NO * NO;
#pragma unroll
        for (int i = 0; i < NO; ++i)
#pragma unroll
            for (int j = 0; j <= i; ++j) M[i][j] = cw[i * NO + j];
#pragma unroll
        for (int l = 0; l < NS; ++l) {
            float vl = va[l];
            float hv[NO];
#pragma unroll
            for (int i = 0; i < NO; ++i) hv[i] = sH[i * NS + l];
#pragma unroll
            for (int i = 0; i < NO; ++i) {
                float hvi = hv[i] * vl;
#pragma unroll
                for (int j = 0; j <= i; ++j) M[i][j] = fmaf(hvi, hv[j], M[i][j]);
            }
        }
        float logdet = 0.0f;
        float drs[NO];
#pragma unroll
        for (int j = 0; j < NO; ++j) {
            float d = M[j][j];
#pragma unroll
            for (int k = 0; k < j; ++k) d = fmaf(-M[j][k], M[j][k], d);
            logdet += __logf(d);
            float rs = __frsqrt_rn(d);
            drs[j] = rs;
            M[j][j] = d * rs;
#pragma unroll
            for (int i = j + 1; i < NO; ++i) {
                float v = M[i][j];
#pragma unroll
                for (int k = 0; k < j; ++k) v = fmaf(-M[i][k], M[j][k], v);
                M[i][j] = v * rs;
            }
        }
        float wv[NO];
        float quad = 0.0f;
#pragma unroll
        for (int i = 0; i < NO; ++i) {
            float v = e[i];
#pragma unroll
            for (int k = 0; k < i; ++k) v = fmaf(-M[i][k], wv[k], v);
            wv[i] = v * drs[i] * rcpf(M[i][i] * drs[i]);
            quad = fmaf(wv[i], wv[i], quad);
        }
        const float SCALE = 0.5f / ((float)BN * (float)TT * (float)NO);
        contrib = -(logdet + quad) * SCALE;
    }

#pragma unroll
    for (int off = 32; off > 0; off >>= 1) contrib += __shfl_down(contrib, off);
    if ((tid & 63) == 0) ssum[tid >> 6] = contrib;
    __syncthreads();
    if (tid == 0) {
        float s = ssum[0] + ssum[1] + ssum[2] + ssum[3];
        atomicAdd(out, s);
    }
}

// ---------------- launch ---------------------------------------------------
extern "C" void kernel_launch(void* const* d_in, const int* in_sizes, int n_in,
                              void* d_out, int out_size, void* d_ws, size_t ws_size,
                              hipStream_t stream) {
    const float* Yi    = (const float*)d_in[0];
    const float* Xh    = (const float*)d_in[1];
    const float* Cw    = (const float*)d_in[2];
    const float* Hm    = (const float*)d_in[3];
    const float* mu_w  = (const float*)d_in[4];
    const float* Wi    = (const float*)d_in[5];
    const float* Wh    = (const float*)d_in[6];
    const float* bi    = (const float*)d_in[7];
    const float* bh    = (const float*)d_in[8];
    const float* W_mu  = (const float*)d_in[9];
    const float* b_mu  = (const float*)d_in[10];
    const float* W_var = (const float*)d_in[11];
    const float* b_var = (const float*)d_in[12];
    float* out = (float*)d_out;
    float* mv  = (float*)d_ws;   // [BN*TT*DIN] floats = 20.48 MB

    const size_t mv_f = (size_t)BN * TT * DIN;          // 5.12M floats
    const size_t xp_f = (size_t)BN * TT * G3;           // 49.152M floats
    const size_t need = (mv_f + xp_f) * sizeof(float);  // 217.1 MB

    init_out<<<1, 1, 0, stream>>>(out);
    if (ws_size >= need) {
        float* xpbuf = mv + mv_f;
        xproj_pre<<<dim3(NBLK * 125), dim3(64), 0, stream>>>(Yi, Xh, Wi, bi, bh, xpbuf);
        gru_rec<<<dim3(NBLK), dim3(256), 0, stream>>>(Wh, bh, W_mu, W_var, xpbuf, mv);
    } else {
        gru_mfma_fb<<<dim3(NBLK), dim3(256), 0, stream>>>(Yi, Xh, Wi, Wh, bi, bh,
                                                          W_mu, W_var, mv);
    }
    lik_phase2<<<dim3((BN * TT + 255) / 256), dim3(256), 0, stream>>>(
        Yi, Cw, Hm, mu_w, b_mu, b_var, mv, out);
}